// Round 5
// baseline (98.737 us; speedup 1.0000x reference)
//
#include <hip/hip_runtime.h>

#define KLEN 64
#define FCH 16            // fine chunk length (steps)
#define WARMUP 48         // S1 contraction ~0.8/step -> 0.8^48 ~ 2e-5 rel
#define WIN_FC 64         // fine chunks per S2 window (= 1024 steps, one wave)
#define WSTEP (WIN_FC * FCH)
#define S1_INIT_V 50.0f
#define S2_INIT_V 250.0f

__device__ __forceinline__ float fpow(float x, float e) {
    // x >= 0; x==0 -> log2=-inf -> exp2=0 (exponents here are > 0)
    return exp2f(e * __log2f(x));
}
__device__ __forceinline__ float clamp01(float x) { return fminf(fmaxf(x, 0.0f), 1.0f); }
__device__ __forceinline__ float physp(const float* __restrict__ raw, int i, float lo, float hi) {
    return lo + (hi - lo) / (1.0f + __expf(-raw[i]));
}

// ---- 8-step forcing group: 24 floats = 6 float4 (16B-aligned when t%8==0) ----
struct F8 { float4 v[6]; };
__device__ __forceinline__ F8 load_f8(const float* __restrict__ forc, int t) {
    const float4* p = (const float4*)(forc + 3 * t);
    F8 r;
#pragma unroll
    for (int k = 0; k < 6; ++k) r.v[k] = p[k];
    return r;
}
__device__ __forceinline__ float f4c(const float4& v, int c) {
    return c == 0 ? v.x : c == 1 ? v.y : c == 2 ? v.z : v.w;
}
__device__ __forceinline__ float f8_get(const F8& f, int i) { return f4c(f.v[i >> 2], i & 3); }

// Monotonic device-scope grid barrier. Grid = NW (<=256) one-wave blocks, all
// co-resident on a 256-CU chip; counter zeroed by hipMemsetAsync pre-launch.
__device__ __forceinline__ void gbar(int* cnt, int phase, int nblk) {
    __syncthreads();
    if (threadIdx.x == 0) {
        __threadfence();
        __hip_atomic_fetch_add(cnt, 1, __ATOMIC_ACQ_REL, __HIP_MEMORY_SCOPE_AGENT);
        while (__hip_atomic_load(cnt, __ATOMIC_ACQUIRE, __HIP_MEMORY_SCOPE_AGENT) <
               phase * nblk) {
            __builtin_amdgcn_s_sleep(2);
        }
        __threadfence();
    }
    __syncthreads();
}

__global__ void __launch_bounds__(64) k_fused(
        const float* __restrict__ forc, const float* __restrict__ raw,
        float* __restrict__ q12f, float* __restrict__ Qw,
        float* __restrict__ S2win, float* __restrict__ qbwin,
        float* __restrict__ s2fine, float* __restrict__ runoff,
        int* __restrict__ syncp, int* __restrict__ flag,
        float* __restrict__ out, int T, int nfine, int NW) {
    __shared__ float r[WSTEP + 64];   // conv input: [0..63]=prev-window tail, [64+i]=step i
    __shared__ float ker[KLEN];
    const int lane = threadIdx.x;
    const int w = blockIdx.x;
    const int j = w * WIN_FC + lane;
    const int t0w = w * WSTEP;
    const bool active = j < nfine;

    // physical params (each thread computes its own; trivially cheap)
    const float S1max  = physp(raw, 0, 50.0f, 5000.0f);
    const float S2max  = physp(raw, 1, 100.0f, 10000.0f);
    const float f_tens = physp(raw, 2, 0.05f, 0.95f);
    const float ku     = physp(raw, 6, 0.01f, 1000.0f);
    const float cc     = physp(raw, 7, 1.0f, 20.0f);
    const float ki     = physp(raw, 11, 0.01f, 1000.0f);
    const float ks     = physp(raw, 12, 0.001f, 10000.0f);
    const float nn     = physp(raw, 13, 1.0f, 10.0f);
    const float b      = physp(raw, 18, 0.001f, 3.0f);
    const float Train  = physp(raw, 22, -2.0f, 4.0f);
    const float invS1 = 1.0f / S1max, invS2 = 1.0f / S2max, invft = 1.0f / f_tens;

#define S1_STEP(pr, pe, te, EXTRA)                                        \
    {                                                                     \
        float rain = (te) > Train ? (pr) : 0.0f;                          \
        float s1f = clamp01(S1 * invS1);                                  \
        float lg = __log2f(s1f);                                          \
        float e1 = (pe)*fminf(s1f * invft, 1.0f);                         \
        float qsx = rain * exp2f(b * lg);                                 \
        float q12 = ku * exp2f(cc * lg);                                  \
        float qif = ki * s1f;                                             \
        EXTRA;                                                            \
        S1 = fminf(fmaxf(S1 + rain - qsx - e1 - q12 - qif, 0.0f), S1max); \
    }

    // ---------------- Phase A: S1 spin-up; keep per-step fluxes in registers ----------------
    float qx[FCH];    // qsx+qif per step (statically indexed -> registers)
    float q12v[FCH];  // q12 per step
    float Q = 0.0f;
    const int t0 = j * FCH;
    const int tend = active ? min(t0 + FCH, T) : t0;
    const bool fullchunk = active && (tend - t0 == FCH);

    if (active) {
        int ts = max(t0 - WARMUP, 0);
        float S1 = S1_INIT_V;
        int ngw = (t0 - ts) >> 3;  // multiple of 8 by construction
        F8 cur = load_f8(forc, ts);
        for (int g = 0; g < ngw; ++g) {
            F8 nxt = load_f8(forc, ts + 8 * (g + 1));  // last prefetch = first main group
#pragma unroll
            for (int s = 0; s < 8; ++s)
                S1_STEP(f8_get(cur, 3 * s), f8_get(cur, 3 * s + 1), f8_get(cur, 3 * s + 2), );
            cur = nxt;
        }
        if (fullchunk) {
#pragma unroll
            for (int g = 0; g < 2; ++g) {
                F8 nxt = (g == 0) ? load_f8(forc, t0 + 8) : cur;
#pragma unroll
                for (int s = 0; s < 8; ++s) {
                    const int idx = 8 * g + s;
                    S1_STEP(f8_get(cur, 3 * s), f8_get(cur, 3 * s + 1), f8_get(cur, 3 * s + 2),
                            qx[idx] = qsx + qif; q12v[idx] = q12; Q += q12);
                }
                cur = nxt;
            }
        } else {  // partial last chunk: no register fluxes (phase C re-sims)
            for (int t = t0; t < tend; ++t) {
                float pr = forc[3 * t], pe = forc[3 * t + 1], te = forc[3 * t + 2];
                S1_STEP(pr, pe, te, Q += q12);
            }
        }
        q12f[j] = Q;  // for the sequential fallback only
    }
    {   // window inflow
        float s = Q;
#pragma unroll
        for (int o = 32; o >= 1; o >>= 1) s += __shfl_xor(s, o, 64);
        if (lane == 0) Qw[w] = s;
    }

    gbar(syncp, 1, NW);

    // ---------------- Phase B: Picard fixed-point for window-start S2 (block 0) ----------------
    if (w == 0) {
        int wsteps = WSTEP;
        int w0 = 2 * lane, w1 = 2 * lane + 1;
        float L0 = (w0 < NW) ? (float)min(wsteps, T - wsteps * w0) : 0.0f;
        float L1 = (w1 < NW) ? (float)min(wsteps, T - wsteps * w1) : 0.0f;
        float Q0 = (w0 < NW) ? Qw[w0] : 0.0f;
        float Q1 = (w1 < NW) ? Qw[w1] : 0.0f;

        float qb0 = ks * fpow(clamp01(S2_INIT_V * invS2), nn);
        float qb1 = qb0;
        float S20 = S2_INIT_V, S21 = S2_INIT_V;
        bool picard_ok = (NW <= 128);
        if (picard_ok) {
            for (int it = 0; it < 12; ++it) {
                float d0 = Q0 - L0 * qb0;
                float d1 = Q1 - L1 * qb1;
                float pair = d0 + d1;
                float sc = pair;  // inclusive lane scan
#pragma unroll
                for (int o = 1; o < 64; o <<= 1) {
                    float v = __shfl_up(sc, o, 64);
                    if (lane >= o) sc += v;
                }
                float excl = sc - pair;
                S20 = S2_INIT_V + excl;
                S21 = S20 + d0;
                qb0 = ks * fpow(clamp01(S20 * invS2), nn);
                qb1 = ks * fpow(clamp01(S21 * invS2), nn);
            }
            bool bad = false;
            if (w0 < NW) bad |= (S20 - L0 * qb0 < 0.5f) || (S20 + Q0 > S2max - 0.5f);
            if (w1 < NW) bad |= (S21 - L1 * qb1 < 0.5f) || (S21 + Q1 > S2max - 0.5f);
            picard_ok = (__ballot(bad) == 0ULL);
        }
        if (picard_ok) {
            if (w0 < NW) { S2win[w0] = S20; qbwin[w0] = qb0; }
            if (w1 < NW) { S2win[w1] = S21; qbwin[w1] = qb1; }
            if (lane == 0) *flag = 0;
        } else if (lane == 0) {
            *flag = 1;  // sequential fallback (clamped, qb frozen per window)
            float S2 = S2_INIT_V;
            for (int v = 0; v < NW; ++v) {
                float s2f = clamp01(S2 * invS2);
                float qb = ks * fpow(s2f, nn);
                S2win[v] = S2; qbwin[v] = qb;
                int i0 = v * WIN_FC, i1 = min(i0 + WIN_FC, nfine);
                for (int i = i0; i < i1; ++i) {
                    s2fine[i] = S2;
                    float steps = (float)min(FCH, T - FCH * i);
                    S2 = fminf(fmaxf(S2 + q12f[i] - steps * qb, 0.0f), S2max);
                }
            }
        }
    }

    gbar(syncp, 2, NW);

    // ---------------- Phase C: per-chunk S2 recursion, emit runoff ----------------
    float S2;
    if (*flag) {
        S2 = active ? s2fine[j] : 0.0f;
    } else {
        float sc = Q;  // wave exclusive prefix of window-local q12
#pragma unroll
        for (int o = 1; o < 64; o <<= 1) {
            float v = __shfl_up(sc, o, 64);
            if (lane >= o) sc += v;
        }
        S2 = S2win[w] + (sc - Q) - qbwin[w] * (float)(FCH * lane);
        S2 = fminf(fmaxf(S2, 0.0f), S2max);
    }
    if (fullchunk) {
        float rb[FCH];
#pragma unroll
        for (int s = 0; s < FCH; ++s) {
            float s2f = clamp01(S2 * invS2);
            float qb = ks * fpow(s2f, nn);
            float ro = qx[s] + qb;
            rb[s] = ro;
            r[64 + FCH * lane + s] = ro;
            S2 = fminf(fmaxf(S2 + q12v[s] - qb, 0.0f), S2max);
        }
        float4* rp = (float4*)(runoff + t0);
#pragma unroll
        for (int s4 = 0; s4 < 4; ++s4)
            rp[s4] = make_float4(rb[4 * s4], rb[4 * s4 + 1], rb[4 * s4 + 2], rb[4 * s4 + 3]);
    } else if (active) {  // partial last chunk: exact re-simulation with S2
        float S1 = S1_INIT_V;
        int ts = max(t0 - WARMUP, 0);
        for (int t = ts; t < t0; ++t) {
            float pr = forc[3 * t], pe = forc[3 * t + 1], te = forc[3 * t + 2];
            S1_STEP(pr, pe, te, );
        }
        for (int t = t0; t < tend; ++t) {
            float pr = forc[3 * t], pe = forc[3 * t + 1], te = forc[3 * t + 2];
            float s2f = clamp01(S2 * invS2);
            float qb = ks * fpow(s2f, nn);
            float ro;
            S1_STEP(pr, pe, te, ro = qsx + qif + qb;
                    S2 = fminf(fmaxf(S2 + q12 - qb, 0.0f), S2max));
            r[64 + (t - t0w)] = ro;
            runoff[t] = ro;
        }
    }

    gbar(syncp, 3, NW);

    // ---------------- Phase D: 64-tap causal gamma conv ----------------
    {   // routing weights (64 lanes = one wave)
        float delay = physp(raw, 21, 0.01f, 5.0f);  // mu_t
        float theta = fmaxf(delay, 1e-3f) * (1.0f / 2.5f);
        float tt = (float)lane + 0.5f;
        float logk = 1.5f * __logf(tt) - tt / theta;
        float m = logk;
#pragma unroll
        for (int o = 32; o >= 1; o >>= 1) m = fmaxf(m, __shfl_xor(m, o, 64));
        float e = __expf(logk - m);
        float s = e;
#pragma unroll
        for (int o = 32; o >= 1; o >>= 1) s += __shfl_xor(s, o, 64);
        ker[lane] = e / s;
        int tp = t0w - 64 + lane;  // previous-window tail (r[0] unused by conv)
        r[lane] = (tp >= 0 && lane > 0) ? runoff[tp] : 0.0f;
    }
    __syncthreads();
#pragma unroll 1
    for (int it = 0; it < WSTEP / 64; ++it) {
        int i = it * 64 + lane;
        int t = t0w + i;
        if (t < T) {
            float acc = 0.0f;
#pragma unroll
            for (int k = 0; k < KLEN; ++k) acc += ker[k] * r[64 + i - k];
            out[t] = acc;
        }
    }
}

extern "C" void kernel_launch(void* const* d_in, const int* in_sizes, int n_in,
                              void* d_out, int out_size, void* d_ws, size_t ws_size,
                              hipStream_t stream) {
    const float* forcing = (const float*)d_in[0];  // [T,3]
    const float* raw = (const float*)d_in[1];      // [29]
    float* out = (float*)d_out;

    int T = in_sizes[0] / 3;
    int nfine = (T + FCH - 1) / FCH;
    int NW = (nfine + WIN_FC - 1) / WIN_FC;   // 128 for T=131072
    int P = ((nfine + 7) / 8) * 8;
    int PW = ((NW + 7) / 8) * 8;

    int* syncp = (int*)d_ws;            // [16] barrier counter
    int* flag = syncp + 16;             // [16]
    float* base = (float*)d_ws + 32;    // 128-byte header keeps 16B alignment
    float* q12f = base;                 // [P]
    float* Qw = q12f + P;               // [PW]
    float* S2win = Qw + PW;             // [PW]
    float* qbwin = S2win + PW;          // [PW]
    float* s2fine = qbwin + PW;         // [P]
    float* runoff = s2fine + P;         // [Tpad]

    hipMemsetAsync(d_ws, 0, 128, stream);  // zero barrier counter + flag (capturable)
    k_fused<<<NW, 64, 0, stream>>>(forcing, raw, q12f, Qw, S2win, qbwin, s2fine,
                                   runoff, syncp, flag, out, T, nfine, NW);
}

// Round 6
// 81.621 us; speedup vs baseline: 1.2097x; 1.2097x over previous
//
#include <hip/hip_runtime.h>

#define KLEN 64
#define FCH 8             // fine chunk length (steps)
#define WARMUP 40         // S1 contraction ~0.802/step -> 0.802^40 ~ 1.5e-4 rel
#define WIN_FC 64         // fine chunks per S2 window (= 512 steps, one wave)
#define WSTEP (WIN_FC * FCH)
#define RHEAD 63          // conv history (prev-window steps 449..511)
#define MAXVW 8           // Picard handles NW <= 64*MAXVW windows
#define S1_INIT_V 50.0f
#define S2_INIT_V 250.0f

__device__ __forceinline__ float fpow(float x, float e) {
    // x >= 0; x==0 -> log2=-inf -> exp2=0 (exponents here are > 0)
    return exp2f(e * __log2f(x));
}
__device__ __forceinline__ float clamp01(float x) { return fminf(fmaxf(x, 0.0f), 1.0f); }
__device__ __forceinline__ float physp(const float* __restrict__ raw, int i, float lo, float hi) {
    return lo + (hi - lo) / (1.0f + __expf(-raw[i]));
}
__device__ __forceinline__ float wave_incl_scan(float x) {
#pragma unroll
    for (int o = 1; o < 64; o <<= 1) {
        float v = __shfl_up(x, o, 64);
        if ((int)threadIdx.x >= o) x += v;
    }
    return x;
}

// ---- 8-step forcing group: 24 floats = 6 float4 (16B-aligned when t%8==0) ----
struct F8 { float4 v[6]; };
__device__ __forceinline__ F8 load_f8(const float* __restrict__ forc, int t) {
    const float4* p = (const float4*)(forc + 3 * t);
    F8 r;
#pragma unroll
    for (int k = 0; k < 6; ++k) r.v[k] = p[k];
    return r;
}
__device__ __forceinline__ float f4c(const float4& v, int c) {
    return c == 0 ? v.x : c == 1 ? v.y : c == 2 ? v.z : v.w;
}
__device__ __forceinline__ float f8_get(const F8& f, int i) { return f4c(f.v[i >> 2], i & 3); }

#define S1_STEP(pr, pe, te, EXTRA)                                        \
    {                                                                     \
        float rain = (te) > Train ? (pr) : 0.0f;                          \
        float s1f = S1 * invS1; /* S1 in [0,S1max] by clamp */            \
        float lg = __log2f(s1f);                                          \
        float e1 = (pe)*fminf(s1f * invft, 1.0f);                         \
        float qsx = rain * exp2f(b * lg);                                 \
        float q12 = ku * exp2f(cc * lg);                                  \
        float qif = ki * s1f;                                             \
        EXTRA;                                                            \
        S1 = fminf(fmaxf(S1 + rain - qsx - e1 - q12 - qif, 0.0f), S1max); \
    }

// ---- Kernel A: per-fine-chunk S1 spin-up; store per-step fluxes + window inflow ----
__global__ void __launch_bounds__(64) k_a(
        const float* __restrict__ forc, const float* __restrict__ raw,
        float* __restrict__ q12f, float* __restrict__ Qw,
        float* __restrict__ fxg, float* __restrict__ q12g, int T, int nfine) {
    const int lane = threadIdx.x;
    const int w = blockIdx.x;
    const int j = w * WIN_FC + lane;
    const bool active = j < nfine;

    const float S1max  = physp(raw, 0, 50.0f, 5000.0f);
    const float f_tens = physp(raw, 2, 0.05f, 0.95f);
    const float ku     = physp(raw, 6, 0.01f, 1000.0f);
    const float cc     = physp(raw, 7, 1.0f, 20.0f);
    const float ki     = physp(raw, 11, 0.01f, 1000.0f);
    const float b      = physp(raw, 18, 0.001f, 3.0f);
    const float Train  = physp(raw, 22, -2.0f, 4.0f);
    const float invS1 = 1.0f / S1max, invft = 1.0f / f_tens;

    float Q = 0.0f;
    if (active) {
        const int t0 = j * FCH;
        const int tend = min(t0 + FCH, T);
        const int ts = max(t0 - WARMUP, 0);
        float S1 = S1_INIT_V;
        if (tend - t0 == FCH) {  // full chunk: vector path, prefetch depth 2
            const int tclamp = ((T - FCH) / FCH) * FCH;  // multiple of 8
            const int ngw = (t0 - ts) >> 3;
            F8 c0 = load_f8(forc, ts);
            F8 c1 = load_f8(forc, min(ts + 8, tclamp));
            for (int g = 0; g < ngw; ++g) {
                F8 c2 = load_f8(forc, min(ts + 8 * (g + 2), tclamp));
#pragma unroll
                for (int s = 0; s < 8; ++s)
                    S1_STEP(f8_get(c0, 3 * s), f8_get(c0, 3 * s + 1), f8_get(c0, 3 * s + 2), );
                c0 = c1; c1 = c2;
            }
            float fxv[8], qv[8];
#pragma unroll
            for (int s = 0; s < 8; ++s)
                S1_STEP(f8_get(c0, 3 * s), f8_get(c0, 3 * s + 1), f8_get(c0, 3 * s + 2),
                        fxv[s] = qsx + qif; qv[s] = q12; Q += q12);
            float4* fx4 = (float4*)fxg;
            float4* q4 = (float4*)q12g;
            fx4[2 * j] = make_float4(fxv[0], fxv[1], fxv[2], fxv[3]);
            fx4[2 * j + 1] = make_float4(fxv[4], fxv[5], fxv[6], fxv[7]);
            q4[2 * j] = make_float4(qv[0], qv[1], qv[2], qv[3]);
            q4[2 * j + 1] = make_float4(qv[4], qv[5], qv[6], qv[7]);
        } else {  // partial last chunk: scalar path
            for (int t = ts; t < t0; ++t) {
                float pr = forc[3 * t], pe = forc[3 * t + 1], te = forc[3 * t + 2];
                S1_STEP(pr, pe, te, );
            }
            for (int t = t0; t < tend; ++t) {
                float pr = forc[3 * t], pe = forc[3 * t + 1], te = forc[3 * t + 2];
                S1_STEP(pr, pe, te, fxg[t] = qsx + qif; q12g[t] = q12; Q += q12);
            }
        }
        q12f[j] = Q;
    }
    float s = Q;
#pragma unroll
    for (int o = 32; o >= 1; o >>= 1) s += __shfl_xor(s, o, 64);
    if (lane == 0) Qw[w] = s;
}

// ---- Kernel B: redundant Picard per block + S2 recursion + local ghost tail + conv ----
__global__ void __launch_bounds__(64) k_b(
        const float* __restrict__ raw, const float* __restrict__ q12f,
        const float* __restrict__ Qw, const float* __restrict__ fxg,
        const float* __restrict__ q12g, float* __restrict__ out,
        int T, int nfine, int NW) {
    __shared__ float r[RHEAD + WSTEP + 1];
    __shared__ float ldsS2[64 * MAXVW], ldsQb[64 * MAXVW];
    __shared__ float ker[KLEN];
    __shared__ float fb[2 * WIN_FC];
    const int lane = threadIdx.x;
    const int w = blockIdx.x;

    const float S2max = physp(raw, 1, 100.0f, 10000.0f);
    const float ks    = physp(raw, 12, 0.001f, 10000.0f);
    const float nn    = physp(raw, 13, 1.0f, 10.0f);
    const float invS2 = 1.0f / S2max;

    // ---- Picard fixed-point over all NW windows (computed redundantly per block) ----
    const int VW = (NW + 63) >> 6;
    bool picard_ok = (VW <= MAXVW);
    if (picard_ok) {
        float S2v[MAXVW], qbv[MAXVW], Qv[MAXVW], Lv[MAXVW];
        const float qb0 = ks * fpow(clamp01(S2_INIT_V * invS2), nn);
        for (int v = 0; v < VW; ++v) {
            int wi = lane * VW + v;
            Lv[v] = (wi < NW) ? (float)min(WSTEP, T - WSTEP * wi) : 0.0f;
            Qv[v] = (wi < NW) ? Qw[wi] : 0.0f;
            S2v[v] = S2_INIT_V; qbv[v] = qb0;
        }
        for (int it = 0; it < 12; ++it) {
            float loc[MAXVW]; float sum = 0.0f;
            for (int v = 0; v < VW; ++v) { loc[v] = sum; sum += Qv[v] - Lv[v] * qbv[v]; }
            float sc = wave_incl_scan(sum);
            float base = S2_INIT_V + (sc - sum);
            for (int v = 0; v < VW; ++v) {
                S2v[v] = base + loc[v];
                qbv[v] = ks * fpow(clamp01(S2v[v] * invS2), nn);
            }
        }
        bool bad = false;
        for (int v = 0; v < VW; ++v) {
            int wi = lane * VW + v;
            if (wi < NW)
                bad |= (S2v[v] - Lv[v] * qbv[v] < 0.5f) || (S2v[v] + Qv[v] > S2max - 0.5f) ||
                       !(S2v[v] == S2v[v]);  // NaN guard (divergent Picard)
        }
        picard_ok = (__ballot(bad) == 0ULL);
        if (picard_ok) {
            for (int v = 0; v < VW; ++v) {
                int wi = lane * VW + v;
                if (wi < NW) { ldsS2[wi] = S2v[v]; ldsQb[wi] = qbv[v]; }
            }
        }
    }
    if (!picard_ok && lane == 0) {
        // sequential fallback: exact chunk-level scan up to end of own window
        float S2 = S2_INIT_V;
        int iend = min((w + 1) * WIN_FC, nfine);
        for (int i = 0; i < iend; ++i) {
            if (w > 0 && i >= (w - 1) * WIN_FC && i < w * WIN_FC) fb[i - (w - 1) * WIN_FC] = S2;
            if (i >= w * WIN_FC) fb[WIN_FC + (i - w * WIN_FC)] = S2;
            float qbc = ks * fpow(clamp01(S2 * invS2), nn);
            float steps = (float)min(FCH, T - FCH * i);
            S2 = fminf(fmaxf(S2 + q12f[i] - steps * qbc, 0.0f), S2max);
        }
    }
    __syncthreads();

    const int j = w * WIN_FC + lane;
    const bool active = j < nfine;

    // own-chunk S2 start: window value + q12 prefix - frozen-qb drain
    float qf = active ? q12f[j] : 0.0f;
    float sc1 = wave_incl_scan(qf);
    float S2own = 0.0f;
    if (active) {
        S2own = picard_ok
            ? fminf(fmaxf(ldsS2[w] + (sc1 - qf) - ldsQb[w] * (float)(FCH * lane), 0.0f), S2max)
            : fb[WIN_FC + lane];
    }
    // ghost-chunk S2 start (previous window, lanes 56..63)
    float S2g = 0.0f;
    if (w > 0) {
        float qfp = q12f[(w - 1) * WIN_FC + lane];
        float sc2 = wave_incl_scan(qfp);
        S2g = picard_ok
            ? fminf(fmaxf(ldsS2[w - 1] + (sc2 - qfp) - ldsQb[w - 1] * (float)(FCH * lane), 0.0f), S2max)
            : fb[lane];
    } else if (lane < RHEAD) {
        r[lane] = 0.0f;  // no history before t=0
    }

    // own 8-step S2 recursion -> runoff into LDS
    {
        const int base_i = FCH * lane;
        if (active) {
            const float4* fx4 = (const float4*)fxg;
            const float4* q4 = (const float4*)q12g;
            float4 fa = fx4[2 * j], fb4 = fx4[2 * j + 1];
            float4 qa = q4[2 * j], qd = q4[2 * j + 1];
            float fxv[8] = {fa.x, fa.y, fa.z, fa.w, fb4.x, fb4.y, fb4.z, fb4.w};
            float qv[8] = {qa.x, qa.y, qa.z, qa.w, qd.x, qd.y, qd.z, qd.w};
            float S2 = S2own;
            int nst = min(FCH, T - FCH * j);
#pragma unroll
            for (int s = 0; s < 8; ++s) {
                float qb = ks * fpow(clamp01(S2 * invS2), nn);
                float ro = fxv[s] + qb;
                r[RHEAD + base_i + s] = (s < nst) ? ro : 0.0f;
                S2 = fminf(fmaxf(S2 + qv[s] - qb, 0.0f), S2max);
            }
        } else {
#pragma unroll
            for (int s = 0; s < 8; ++s) r[RHEAD + base_i + s] = 0.0f;
        }
    }
    // ghost recursion: previous window's last 64 steps (always full chunks)
    if (w > 0 && lane >= WIN_FC - 8) {
        int jg = (w - 1) * WIN_FC + lane;
        const float4* fx4 = (const float4*)fxg;
        const float4* q4 = (const float4*)q12g;
        float4 fa = fx4[2 * jg], fb4 = fx4[2 * jg + 1];
        float4 qa = q4[2 * jg], qd = q4[2 * jg + 1];
        float fxv[8] = {fa.x, fa.y, fa.z, fa.w, fb4.x, fb4.y, fb4.z, fb4.w};
        float qv[8] = {qa.x, qa.y, qa.z, qa.w, qd.x, qd.y, qd.z, qd.w};
        float S2 = S2g;
#pragma unroll
        for (int s = 0; s < 8; ++s) {
            float qb = ks * fpow(clamp01(S2 * invS2), nn);
            float ro = fxv[s] + qb;
            int p = FCH * lane + s;         // prev-window step index in [448,512)
            if (p >= WSTEP - RHEAD) r[p - (WSTEP - RHEAD)] = ro;
            S2 = fminf(fmaxf(S2 + qv[s] - qb, 0.0f), S2max);
        }
    }
    // routing weights (64 lanes = one wave)
    {
        float delay = physp(raw, 21, 0.01f, 5.0f);  // mu_t
        float theta = fmaxf(delay, 1e-3f) * (1.0f / 2.5f);
        float tt = (float)lane + 0.5f;
        float logk = 1.5f * __logf(tt) - tt / theta;
        float m = logk;
#pragma unroll
        for (int o = 32; o >= 1; o >>= 1) m = fmaxf(m, __shfl_xor(m, o, 64));
        float e = __expf(logk - m);
        float s = e;
#pragma unroll
        for (int o = 32; o >= 1; o >>= 1) s += __shfl_xor(s, o, 64);
        ker[lane] = e / s;
    }
    __syncthreads();

    // 64-tap causal conv from LDS
#pragma unroll 1
    for (int it = 0; it < WSTEP / 64; ++it) {
        int i = it * 64 + lane;
        int t = w * WSTEP + i;
        if (t < T) {
            float acc = 0.0f;
#pragma unroll
            for (int k = 0; k < KLEN; ++k) acc += ker[k] * r[RHEAD + i - k];
            out[t] = acc;
        }
    }
}

extern "C" void kernel_launch(void* const* d_in, const int* in_sizes, int n_in,
                              void* d_out, int out_size, void* d_ws, size_t ws_size,
                              hipStream_t stream) {
    const float* forcing = (const float*)d_in[0];  // [T,3]
    const float* raw = (const float*)d_in[1];      // [29]
    float* out = (float*)d_out;
    float* ws = (float*)d_ws;

    int T = in_sizes[0] / 3;
    int nfine = (T + FCH - 1) / FCH;              // 16384 for T=131072
    int NW = (nfine + WIN_FC - 1) / WIN_FC;       // 256
    int P = ((nfine + 15) / 16) * 16;
    int PW = ((NW + 15) / 16) * 16;
    int Tp = P * FCH;

    float* q12f = ws;            // [P]   per-chunk q12 sum
    float* Qw = q12f + P;        // [PW]  per-window inflow
    float* fxg = Qw + PW;        // [Tp]  per-step qsx+qif
    float* q12g = fxg + Tp;      // [Tp]  per-step q12

    k_a<<<NW, 64, 0, stream>>>(forcing, raw, q12f, Qw, fxg, q12g, T, nfine);
    k_b<<<NW, 64, 0, stream>>>(raw, q12f, Qw, fxg, q12g, out, T, nfine, NW);
}

// Round 7
// 77.371 us; speedup vs baseline: 1.2761x; 1.0549x over previous
//
#include <hip/hip_runtime.h>

#define KLEN 64
#define FCH 8             // fine chunk length (steps)
#define WARMUP 40         // S1 contraction ~0.802/step -> 0.802^40 ~ 1.5e-4 rel
#define WIN_FC 64         // fine chunks per S2 window (= 512 steps, one wave)
#define WSTEP (WIN_FC * FCH)
#define MAXVW 8           // Picard handles NW <= 64*MAXVW windows
#define ROWS 72           // LDS row stride (chunks per window + ghost row + pad)
#define S1_INIT_V 50.0f
#define S2_INIT_V 250.0f

__device__ __forceinline__ float fpow(float x, float e) {
    // x >= 0; x==0 -> log2=-inf -> exp2=0 (exponents here are > 0)
    return exp2f(e * __log2f(x));
}
__device__ __forceinline__ float clamp01(float x) { return fminf(fmaxf(x, 0.0f), 1.0f); }
__device__ __forceinline__ float physp(const float* __restrict__ raw, int i, float lo, float hi) {
    return lo + (hi - lo) / (1.0f + __expf(-raw[i]));
}
__device__ __forceinline__ float wave_incl_scan(float x) {
#pragma unroll
    for (int o = 1; o < 64; o <<= 1) {
        float v = __shfl_up(x, o, 64);
        if ((int)threadIdx.x >= o) x += v;
    }
    return x;
}

// ---- 8-step forcing group: 24 floats = 6 float4 (16B-aligned when t%8==0) ----
struct F8 { float4 v[6]; };
__device__ __forceinline__ F8 load_f8(const float* __restrict__ forc, int t) {
    const float4* p = (const float4*)(forc + 3 * t);
    F8 r;
#pragma unroll
    for (int k = 0; k < 6; ++k) r.v[k] = p[k];
    return r;
}
__device__ __forceinline__ float f4c(const float4& v, int c) {
    return c == 0 ? v.x : c == 1 ? v.y : c == 2 ? v.z : v.w;
}
__device__ __forceinline__ float f8_get(const F8& f, int i) { return f4c(f.v[i >> 2], i & 3); }

#define S1_STEP(pr, pe, te, EXTRA)                                        \
    {                                                                     \
        float rain = (te) > Train ? (pr) : 0.0f;                          \
        float s1f = S1 * invS1; /* S1 in [0,S1max] by clamp */            \
        float lg = __log2f(s1f);                                          \
        float e1 = (pe)*fminf(s1f * invft, 1.0f);                         \
        float qsx = rain * exp2f(b * lg);                                 \
        float q12 = ku * exp2f(cc * lg);                                  \
        float qif = ki * s1f;                                             \
        EXTRA;                                                            \
        S1 = fminf(fmaxf(S1 + rain - qsx - e1 - q12 - qif, 0.0f), S1max); \
    }

// ---- Kernel A: per-fine-chunk S1 spin-up; store per-step fluxes + window inflow ----
__global__ void __launch_bounds__(64) k_a(
        const float* __restrict__ forc, const float* __restrict__ raw,
        float* __restrict__ q12f, float* __restrict__ Qw,
        float* __restrict__ fxg, float* __restrict__ q12g, int T, int nfine) {
    const int lane = threadIdx.x;
    const int w = blockIdx.x;
    const int j = w * WIN_FC + lane;
    const bool active = j < nfine;

    const float S1max  = physp(raw, 0, 50.0f, 5000.0f);
    const float f_tens = physp(raw, 2, 0.05f, 0.95f);
    const float ku     = physp(raw, 6, 0.01f, 1000.0f);
    const float cc     = physp(raw, 7, 1.0f, 20.0f);
    const float ki     = physp(raw, 11, 0.01f, 1000.0f);
    const float b      = physp(raw, 18, 0.001f, 3.0f);
    const float Train  = physp(raw, 22, -2.0f, 4.0f);
    const float invS1 = 1.0f / S1max, invft = 1.0f / f_tens;

    float Q = 0.0f;
    if (active) {
        const int t0 = j * FCH;
        const int tend = min(t0 + FCH, T);
        const int ts = max(t0 - WARMUP, 0);
        float S1 = S1_INIT_V;
        if (tend - t0 == FCH) {  // full chunk: vector path, prefetch depth 2
            const int tclamp = ((T - FCH) / FCH) * FCH;  // multiple of 8
            const int ngw = (t0 - ts) >> 3;
            F8 c0 = load_f8(forc, ts);
            F8 c1 = load_f8(forc, min(ts + 8, tclamp));
            for (int g = 0; g < ngw; ++g) {
                F8 c2 = load_f8(forc, min(ts + 8 * (g + 2), tclamp));
#pragma unroll
                for (int s = 0; s < 8; ++s)
                    S1_STEP(f8_get(c0, 3 * s), f8_get(c0, 3 * s + 1), f8_get(c0, 3 * s + 2), );
                c0 = c1; c1 = c2;
            }
            float fxv[8], qv[8];
#pragma unroll
            for (int s = 0; s < 8; ++s)
                S1_STEP(f8_get(c0, 3 * s), f8_get(c0, 3 * s + 1), f8_get(c0, 3 * s + 2),
                        fxv[s] = qsx + qif; qv[s] = q12; Q += q12);
            float4* fx4 = (float4*)fxg;
            float4* q4 = (float4*)q12g;
            fx4[2 * j] = make_float4(fxv[0], fxv[1], fxv[2], fxv[3]);
            fx4[2 * j + 1] = make_float4(fxv[4], fxv[5], fxv[6], fxv[7]);
            q4[2 * j] = make_float4(qv[0], qv[1], qv[2], qv[3]);
            q4[2 * j + 1] = make_float4(qv[4], qv[5], qv[6], qv[7]);
        } else {  // partial last chunk: scalar path
            for (int t = ts; t < t0; ++t) {
                float pr = forc[3 * t], pe = forc[3 * t + 1], te = forc[3 * t + 2];
                S1_STEP(pr, pe, te, );
            }
            for (int t = t0; t < tend; ++t) {
                float pr = forc[3 * t], pe = forc[3 * t + 1], te = forc[3 * t + 2];
                S1_STEP(pr, pe, te, fxg[t] = qsx + qif; q12g[t] = q12; Q += q12);
            }
        }
        q12f[j] = Q;
    }
    float s = Q;
#pragma unroll
    for (int o = 32; o >= 1; o >>= 1) s += __shfl_xor(s, o, 64);
    if (lane == 0) Qw[w] = s;
}

// ---- Kernel B: redundant Picard + S2 recursion + ghost tail + sliding-window conv ----
// LDS time map: step i (own window, i in [-64,512)) -> m=i+64 -> rr[(m&7)*ROWS + (m>>3)]
__global__ void __launch_bounds__(64) k_b(
        const float* __restrict__ raw, const float* __restrict__ q12f,
        const float* __restrict__ Qw, const float* __restrict__ fxg,
        const float* __restrict__ q12g, float* __restrict__ out,
        int T, int nfine, int NW) {
    __shared__ float rr[8 * ROWS];
    __shared__ float ldsS2[64 * MAXVW], ldsQb[64 * MAXVW];
    __shared__ float fb[2 * WIN_FC];
    const int lane = threadIdx.x;
    const int w = blockIdx.x;

    const float S2max = physp(raw, 1, 100.0f, 10000.0f);
    const float ks    = physp(raw, 12, 0.001f, 10000.0f);
    const float nn    = physp(raw, 13, 1.0f, 10.0f);
    const float invS2 = 1.0f / S2max;

    // ---- Picard fixed-point over all NW windows (computed redundantly per block) ----
    const int VW = (NW + 63) >> 6;
    bool picard_ok = (VW <= MAXVW);
    if (picard_ok) {
        float S2v[MAXVW], qbv[MAXVW], Qv[MAXVW], Lv[MAXVW];
        const float qb0 = ks * fpow(clamp01(S2_INIT_V * invS2), nn);
        for (int v = 0; v < VW; ++v) {
            int wi = lane * VW + v;
            Lv[v] = (wi < NW) ? (float)min(WSTEP, T - WSTEP * wi) : 0.0f;
            Qv[v] = (wi < NW) ? Qw[wi] : 0.0f;
            S2v[v] = S2_INIT_V; qbv[v] = qb0;
        }
        for (int it = 0; it < 10; ++it) {
            float loc[MAXVW]; float sum = 0.0f;
            for (int v = 0; v < VW; ++v) { loc[v] = sum; sum += Qv[v] - Lv[v] * qbv[v]; }
            float sc = wave_incl_scan(sum);
            float base = S2_INIT_V + (sc - sum);
            for (int v = 0; v < VW; ++v) {
                S2v[v] = base + loc[v];
                qbv[v] = ks * fpow(clamp01(S2v[v] * invS2), nn);
            }
        }
        bool bad = false;
        for (int v = 0; v < VW; ++v) {
            int wi = lane * VW + v;
            if (wi < NW)
                bad |= (S2v[v] - Lv[v] * qbv[v] < 0.5f) || (S2v[v] + Qv[v] > S2max - 0.5f) ||
                       !(S2v[v] == S2v[v]);  // NaN guard (divergent Picard)
        }
        picard_ok = (__ballot(bad) == 0ULL);
        if (picard_ok) {
            for (int v = 0; v < VW; ++v) {
                int wi = lane * VW + v;
                if (wi < NW) { ldsS2[wi] = S2v[v]; ldsQb[wi] = qbv[v]; }
            }
        }
    }
    if (!picard_ok && lane == 0) {
        // sequential fallback: exact chunk-level scan up to end of own window
        float S2 = S2_INIT_V;
        int iend = min((w + 1) * WIN_FC, nfine);
        for (int i = 0; i < iend; ++i) {
            if (w > 0 && i >= (w - 1) * WIN_FC && i < w * WIN_FC) fb[i - (w - 1) * WIN_FC] = S2;
            if (i >= w * WIN_FC) fb[WIN_FC + (i - w * WIN_FC)] = S2;
            float qbc = ks * fpow(clamp01(S2 * invS2), nn);
            float steps = (float)min(FCH, T - FCH * i);
            S2 = fminf(fmaxf(S2 + q12f[i] - steps * qbc, 0.0f), S2max);
        }
    }
    __syncthreads();

    const int j = w * WIN_FC + lane;
    const bool active = j < nfine;

    // own-chunk S2 start: window value + q12 prefix - frozen-qb drain
    float qf = active ? q12f[j] : 0.0f;
    float sc1 = wave_incl_scan(qf);
    float S2own = 0.0f;
    if (active) {
        S2own = picard_ok
            ? fminf(fmaxf(ldsS2[w] + (sc1 - qf) - ldsQb[w] * (float)(FCH * lane), 0.0f), S2max)
            : fb[WIN_FC + lane];
    }
    // ghost-chunk S2 start (previous window)
    float S2g = 0.0f;
    if (w > 0) {
        float qfp = q12f[(w - 1) * WIN_FC + lane];
        float sc2 = wave_incl_scan(qfp);
        S2g = picard_ok
            ? fminf(fmaxf(ldsS2[w - 1] + (sc2 - qfp) - ldsQb[w - 1] * (float)(FCH * lane), 0.0f), S2max)
            : fb[lane];
    } else {
        rr[(lane & 7) * ROWS + (lane >> 3)] = 0.0f;  // zero history rows (m in [0,64))
    }

    // own 8-step S2 recursion -> rr[s*ROWS + lane + 8] (conflict-free: lane-consecutive)
    if (active) {
        const float4* fx4 = (const float4*)fxg;
        const float4* q4 = (const float4*)q12g;
        float4 fa = fx4[2 * j], fb4 = fx4[2 * j + 1];
        float4 qa = q4[2 * j], qd = q4[2 * j + 1];
        float fxv[8] = {fa.x, fa.y, fa.z, fa.w, fb4.x, fb4.y, fb4.z, fb4.w};
        float qv[8] = {qa.x, qa.y, qa.z, qa.w, qd.x, qd.y, qd.z, qd.w};
        float S2 = S2own;
        int nst = min(FCH, T - FCH * j);
#pragma unroll
        for (int s = 0; s < 8; ++s) {
            float qb = ks * fpow(S2 * invS2, nn);  // S2 in [0,S2max] by clamp
            float ro = fxv[s] + qb;
            rr[s * ROWS + lane + 8] = (s < nst) ? ro : 0.0f;
            S2 = fminf(fmaxf(S2 + qv[s] - qb, 0.0f), S2max);
        }
    } else {
#pragma unroll
        for (int s = 0; s < 8; ++s) rr[s * ROWS + lane + 8] = 0.0f;
    }
    // ghost recursion: previous window's last 8 chunks -> rr rows 0..7 (m in [0,64))
    if (w > 0 && lane >= WIN_FC - 8) {
        int jg = (w - 1) * WIN_FC + lane;
        const float4* fx4 = (const float4*)fxg;
        const float4* q4 = (const float4*)q12g;
        float4 fa = fx4[2 * jg], fb4 = fx4[2 * jg + 1];
        float4 qa = q4[2 * jg], qd = q4[2 * jg + 1];
        float fxv[8] = {fa.x, fa.y, fa.z, fa.w, fb4.x, fb4.y, fb4.z, fb4.w};
        float qv[8] = {qa.x, qa.y, qa.z, qa.w, qd.x, qd.y, qd.z, qd.w};
        float S2 = S2g;
#pragma unroll
        for (int s = 0; s < 8; ++s) {
            float qb = ks * fpow(S2 * invS2, nn);
            rr[s * ROWS + (lane - (WIN_FC - 8))] = fxv[s] + qb;
            S2 = fminf(fmaxf(S2 + qv[s] - qb, 0.0f), S2max);
        }
    }
    // routing weights: lane holds ker[lane] in a register (readlane'd in the conv)
    float kreg;
    {
        float delay = physp(raw, 21, 0.01f, 5.0f);  // mu_t
        float theta = fmaxf(delay, 1e-3f) * (1.0f / 2.5f);
        float tt = (float)lane + 0.5f;
        float logk = 1.5f * __logf(tt) - tt / theta;
        float m = logk;
#pragma unroll
        for (int o = 32; o >= 1; o >>= 1) m = fmaxf(m, __shfl_xor(m, o, 64));
        float e = __expf(logk - m);
        float su = e;
#pragma unroll
        for (int o = 32; o >= 1; o >>= 1) su += __shfl_xor(su, o, 64);
        kreg = e / su;
    }
    __syncthreads();

    // ---- 64-tap conv, register sliding window: lane computes its own chunk's 8 outputs ----
    // y[s] = sum_k ker[k] * x[8*lane+s-k]; j-loop (j=63-k) slides window up by 1/iter.
    {
        float y[8];
#pragma unroll
        for (int s = 0; s < 8; ++s) y[s] = 0.0f;
        float wdw[8];
        // initial window: x[8*lane-63 .. 8*lane-56]  (m = 8*lane+1+e)
#pragma unroll
        for (int e = 0; e < 8; ++e) {
            int m = 8 * lane + 1 + e;
            wdw[e] = rr[(m & 7) * ROWS + (m >> 3)];
        }
#pragma unroll
        for (int jj = 0; jj < 64; ++jj) {
            float kk = __shfl(kreg, 63 - jj, 64);  // wave-uniform -> readlane -> SGPR
#pragma unroll
            for (int s = 0; s < 8; ++s) y[s] += kk * wdw[(jj + s) & 7];
            if (jj < 63) {
                int m = 8 * lane + 9 + jj;  // new element x[8*lane-55+jj]
                wdw[jj & 7] = rr[(m & 7) * ROWS + (m >> 3)];
            }
        }
        int tb = w * WSTEP + 8 * lane;
        if (tb + 8 <= T) {
            float4* op = (float4*)(out + tb);
            op[0] = make_float4(y[0], y[1], y[2], y[3]);
            op[1] = make_float4(y[4], y[5], y[6], y[7]);
        } else {
            for (int s = 0; s < 8; ++s)
                if (tb + s < T) out[tb + s] = y[s];
        }
    }
}

extern "C" void kernel_launch(void* const* d_in, const int* in_sizes, int n_in,
                              void* d_out, int out_size, void* d_ws, size_t ws_size,
                              hipStream_t stream) {
    const float* forcing = (const float*)d_in[0];  // [T,3]
    const float* raw = (const float*)d_in[1];      // [29]
    float* out = (float*)d_out;
    float* ws = (float*)d_ws;

    int T = in_sizes[0] / 3;
    int nfine = (T + FCH - 1) / FCH;              // 16384 for T=131072
    int NW = (nfine + WIN_FC - 1) / WIN_FC;       // 256
    int P = ((nfine + 15) / 16) * 16;
    int PW = ((NW + 15) / 16) * 16;
    int Tp = P * FCH;

    float* q12f = ws;            // [P]   per-chunk q12 sum
    float* Qw = q12f + P;        // [PW]  per-window inflow
    float* fxg = Qw + PW;        // [Tp]  per-step qsx+qif
    float* q12g = fxg + Tp;      // [Tp]  per-step q12

    k_a<<<NW, 64, 0, stream>>>(forcing, raw, q12f, Qw, fxg, q12g, T, nfine);
    k_b<<<NW, 64, 0, stream>>>(raw, q12f, Qw, fxg, q12g, out, T, nfine, NW);
}

// Round 8
// 74.625 us; speedup vs baseline: 1.3231x; 1.0368x over previous
//
#include <hip/hip_runtime.h>

#define KLEN 64
#define FCH 8             // fine chunk length (steps)
#define WARMUP 40         // S1 contraction ~0.802/step -> 0.802^40 ~ 1.5e-4 rel
#define WIN_FC 64         // fine chunks per S2 window (= 512 steps, one wave)
#define WSTEP (WIN_FC * FCH)
#define MAXVW 8           // Picard handles NW <= 64*MAXVW windows
#define ROWS 72           // LDS row stride (chunks per window + ghost row + pad)
#define S1_INIT_V 50.0f
#define S2_INIT_V 250.0f

// Raw transcendental units: v_exp_f32 computes 2^x, v_log_f32 computes log2(x).
// OCML exp2f/log2f add denormal-fixup chains; at ~0.3 GHz effective clock the
// extra ~20 chain cycles/step dominate (see R8 theory).
#if __has_builtin(__builtin_amdgcn_exp2f)
#define EXP2F(x) __builtin_amdgcn_exp2f(x)
#else
#define EXP2F(x) exp2f(x)
#endif
#if __has_builtin(__builtin_amdgcn_logf)
#define LOG2F(x) __builtin_amdgcn_logf(x)
#else
#define LOG2F(x) __log2f(x)
#endif

__device__ __forceinline__ float fpow(float x, float e) {
    // x >= 0; x==0 -> log2=-inf -> exp2=0 (exponents here are > 0)
    return EXP2F(e * LOG2F(x));
}
__device__ __forceinline__ float clamp01(float x) { return fminf(fmaxf(x, 0.0f), 1.0f); }
__device__ __forceinline__ float physp(const float* __restrict__ raw, int i, float lo, float hi) {
    return lo + (hi - lo) / (1.0f + __expf(-raw[i]));
}
__device__ __forceinline__ float wave_incl_scan(float x) {
#pragma unroll
    for (int o = 1; o < 64; o <<= 1) {
        float v = __shfl_up(x, o, 64);
        if ((int)threadIdx.x >= o) x += v;
    }
    return x;
}

// ---- 8-step forcing group: 24 floats = 6 float4 (16B-aligned when t%8==0) ----
struct F8 { float4 v[6]; };
__device__ __forceinline__ F8 load_f8(const float* __restrict__ forc, int t) {
    const float4* p = (const float4*)(forc + 3 * t);
    F8 r;
#pragma unroll
    for (int k = 0; k < 6; ++k) r.v[k] = p[k];
    return r;
}
__device__ __forceinline__ float f4c(const float4& v, int c) {
    return c == 0 ? v.x : c == 1 ? v.y : c == 2 ? v.z : v.w;
}
__device__ __forceinline__ float f8_get(const F8& f, int i) { return f4c(f.v[i >> 2], i & 3); }

#define S1_STEP(pr, pe, te, EXTRA)                                        \
    {                                                                     \
        float rain = (te) > Train ? (pr) : 0.0f;                          \
        float s1f = S1 * invS1; /* S1 in [0,S1max] by clamp */            \
        float lg = LOG2F(s1f);                                            \
        float e1 = (pe)*fminf(s1f * invft, 1.0f);                         \
        float qsx = rain * EXP2F(b * lg);                                 \
        float q12 = ku * EXP2F(cc * lg);                                  \
        float qif = ki * s1f;                                             \
        EXTRA;                                                            \
        S1 = fminf(fmaxf(S1 + rain - qsx - e1 - q12 - qif, 0.0f), S1max); \
    }

// ---- Kernel A: per-fine-chunk S1 spin-up; store per-step fluxes + window inflow ----
__global__ void __launch_bounds__(64) k_a(
        const float* __restrict__ forc, const float* __restrict__ raw,
        float* __restrict__ q12f, float* __restrict__ Qw,
        float* __restrict__ fxg, float* __restrict__ q12g, int T, int nfine) {
    const int lane = threadIdx.x;
    const int w = blockIdx.x;
    const int j = w * WIN_FC + lane;
    const bool active = j < nfine;

    const float S1max  = physp(raw, 0, 50.0f, 5000.0f);
    const float f_tens = physp(raw, 2, 0.05f, 0.95f);
    const float ku     = physp(raw, 6, 0.01f, 1000.0f);
    const float cc     = physp(raw, 7, 1.0f, 20.0f);
    const float ki     = physp(raw, 11, 0.01f, 1000.0f);
    const float b      = physp(raw, 18, 0.001f, 3.0f);
    const float Train  = physp(raw, 22, -2.0f, 4.0f);
    const float invS1 = 1.0f / S1max, invft = 1.0f / f_tens;

    float Q = 0.0f;
    if (active) {
        const int t0 = j * FCH;
        const int tend = min(t0 + FCH, T);
        const int ts = max(t0 - WARMUP, 0);
        float S1 = S1_INIT_V;
        if (tend - t0 == FCH) {  // full chunk: vector path, prefetch depth 2
            const int tclamp = ((T - FCH) / FCH) * FCH;  // multiple of 8
            const int ngw = (t0 - ts) >> 3;
            F8 c0 = load_f8(forc, ts);
            F8 c1 = load_f8(forc, min(ts + 8, tclamp));
            for (int g = 0; g < ngw; ++g) {
                F8 c2 = load_f8(forc, min(ts + 8 * (g + 2), tclamp));
#pragma unroll
                for (int s = 0; s < 8; ++s)
                    S1_STEP(f8_get(c0, 3 * s), f8_get(c0, 3 * s + 1), f8_get(c0, 3 * s + 2), );
                c0 = c1; c1 = c2;
            }
            float fxv[8], qv[8];
#pragma unroll
            for (int s = 0; s < 8; ++s)
                S1_STEP(f8_get(c0, 3 * s), f8_get(c0, 3 * s + 1), f8_get(c0, 3 * s + 2),
                        fxv[s] = qsx + qif; qv[s] = q12; Q += q12);
            float4* fx4 = (float4*)fxg;
            float4* q4 = (float4*)q12g;
            fx4[2 * j] = make_float4(fxv[0], fxv[1], fxv[2], fxv[3]);
            fx4[2 * j + 1] = make_float4(fxv[4], fxv[5], fxv[6], fxv[7]);
            q4[2 * j] = make_float4(qv[0], qv[1], qv[2], qv[3]);
            q4[2 * j + 1] = make_float4(qv[4], qv[5], qv[6], qv[7]);
        } else {  // partial last chunk: scalar path
            for (int t = ts; t < t0; ++t) {
                float pr = forc[3 * t], pe = forc[3 * t + 1], te = forc[3 * t + 2];
                S1_STEP(pr, pe, te, );
            }
            for (int t = t0; t < tend; ++t) {
                float pr = forc[3 * t], pe = forc[3 * t + 1], te = forc[3 * t + 2];
                S1_STEP(pr, pe, te, fxg[t] = qsx + qif; q12g[t] = q12; Q += q12);
            }
        }
        q12f[j] = Q;
    }
    float s = Q;
#pragma unroll
    for (int o = 32; o >= 1; o >>= 1) s += __shfl_xor(s, o, 64);
    if (lane == 0) Qw[w] = s;
}

// ---- Kernel B: redundant Picard + S2 recursion + ghost tail + sliding-window conv ----
// LDS time map: step i (own window, i in [-64,512)) -> m=i+64 -> rr[(m&7)*ROWS + (m>>3)]
__global__ void __launch_bounds__(64) k_b(
        const float* __restrict__ raw, const float* __restrict__ q12f,
        const float* __restrict__ Qw, const float* __restrict__ fxg,
        const float* __restrict__ q12g, float* __restrict__ out,
        int T, int nfine, int NW) {
    __shared__ float rr[8 * ROWS];
    __shared__ float ldsS2[64 * MAXVW], ldsQb[64 * MAXVW];
    __shared__ float fb[2 * WIN_FC];
    __shared__ float kerL[KLEN];
    const int lane = threadIdx.x;
    const int w = blockIdx.x;

    const float S2max = physp(raw, 1, 100.0f, 10000.0f);
    const float ks    = physp(raw, 12, 0.001f, 10000.0f);
    const float nn    = physp(raw, 13, 1.0f, 10.0f);
    const float invS2 = 1.0f / S2max;

    // ---- Picard fixed-point over all NW windows (computed redundantly per block) ----
    const int VW = (NW + 63) >> 6;
    bool picard_ok = (VW <= MAXVW);
    if (picard_ok) {
        float S2v[MAXVW], qbv[MAXVW], Qv[MAXVW], Lv[MAXVW];
        const float qb0 = ks * fpow(clamp01(S2_INIT_V * invS2), nn);
        for (int v = 0; v < VW; ++v) {
            int wi = lane * VW + v;
            Lv[v] = (wi < NW) ? (float)min(WSTEP, T - WSTEP * wi) : 0.0f;
            Qv[v] = (wi < NW) ? Qw[wi] : 0.0f;
            S2v[v] = S2_INIT_V; qbv[v] = qb0;
        }
        for (int it = 0; it < 8; ++it) {
            float loc[MAXVW]; float sum = 0.0f;
            for (int v = 0; v < VW; ++v) { loc[v] = sum; sum += Qv[v] - Lv[v] * qbv[v]; }
            float sc = wave_incl_scan(sum);
            float base = S2_INIT_V + (sc - sum);
            for (int v = 0; v < VW; ++v) {
                S2v[v] = base + loc[v];
                qbv[v] = ks * fpow(clamp01(S2v[v] * invS2), nn);
            }
        }
        bool bad = false;
        for (int v = 0; v < VW; ++v) {
            int wi = lane * VW + v;
            if (wi < NW)
                bad |= (S2v[v] - Lv[v] * qbv[v] < 0.5f) || (S2v[v] + Qv[v] > S2max - 0.5f) ||
                       !(S2v[v] == S2v[v]);  // NaN guard (divergent Picard)
        }
        picard_ok = (__ballot(bad) == 0ULL);
        if (picard_ok) {
            for (int v = 0; v < VW; ++v) {
                int wi = lane * VW + v;
                if (wi < NW) { ldsS2[wi] = S2v[v]; ldsQb[wi] = qbv[v]; }
            }
        }
    }
    if (!picard_ok && lane == 0) {
        // sequential fallback: exact chunk-level scan up to end of own window
        float S2 = S2_INIT_V;
        int iend = min((w + 1) * WIN_FC, nfine);
        for (int i = 0; i < iend; ++i) {
            if (w > 0 && i >= (w - 1) * WIN_FC && i < w * WIN_FC) fb[i - (w - 1) * WIN_FC] = S2;
            if (i >= w * WIN_FC) fb[WIN_FC + (i - w * WIN_FC)] = S2;
            float qbc = ks * fpow(clamp01(S2 * invS2), nn);
            float steps = (float)min(FCH, T - FCH * i);
            S2 = fminf(fmaxf(S2 + q12f[i] - steps * qbc, 0.0f), S2max);
        }
    }
    __syncthreads();

    const int j = w * WIN_FC + lane;
    const bool active = j < nfine;

    // own-chunk S2 start: window value + q12 prefix - frozen-qb drain
    float qf = active ? q12f[j] : 0.0f;
    float sc1 = wave_incl_scan(qf);
    float S2own = 0.0f;
    if (active) {
        S2own = picard_ok
            ? fminf(fmaxf(ldsS2[w] + (sc1 - qf) - ldsQb[w] * (float)(FCH * lane), 0.0f), S2max)
            : fb[WIN_FC + lane];
    }
    // ghost-chunk S2 start (previous window)
    float S2g = 0.0f;
    if (w > 0) {
        float qfp = q12f[(w - 1) * WIN_FC + lane];
        float sc2 = wave_incl_scan(qfp);
        S2g = picard_ok
            ? fminf(fmaxf(ldsS2[w - 1] + (sc2 - qfp) - ldsQb[w - 1] * (float)(FCH * lane), 0.0f), S2max)
            : fb[lane];
    } else {
        rr[(lane & 7) * ROWS + (lane >> 3)] = 0.0f;  // zero history rows (m in [0,64))
    }

    // own 8-step S2 recursion -> rr[s*ROWS + lane + 8] (conflict-free: lane-consecutive)
    if (active) {
        const float4* fx4 = (const float4*)fxg;
        const float4* q4 = (const float4*)q12g;
        float4 fa = fx4[2 * j], fb4 = fx4[2 * j + 1];
        float4 qa = q4[2 * j], qd = q4[2 * j + 1];
        float fxv[8] = {fa.x, fa.y, fa.z, fa.w, fb4.x, fb4.y, fb4.z, fb4.w};
        float qv[8] = {qa.x, qa.y, qa.z, qa.w, qd.x, qd.y, qd.z, qd.w};
        float S2 = S2own;
        int nst = min(FCH, T - FCH * j);
#pragma unroll
        for (int s = 0; s < 8; ++s) {
            float qb = ks * fpow(S2 * invS2, nn);  // S2 in [0,S2max] by clamp
            float ro = fxv[s] + qb;
            rr[s * ROWS + lane + 8] = (s < nst) ? ro : 0.0f;
            S2 = fminf(fmaxf(S2 + qv[s] - qb, 0.0f), S2max);
        }
    } else {
#pragma unroll
        for (int s = 0; s < 8; ++s) rr[s * ROWS + lane + 8] = 0.0f;
    }
    // ghost recursion: previous window's last 8 chunks -> rr rows 0..7 (m in [0,64))
    if (w > 0 && lane >= WIN_FC - 8) {
        int jg = (w - 1) * WIN_FC + lane;
        const float4* fx4 = (const float4*)fxg;
        const float4* q4 = (const float4*)q12g;
        float4 fa = fx4[2 * jg], fb4 = fx4[2 * jg + 1];
        float4 qa = q4[2 * jg], qd = q4[2 * jg + 1];
        float fxv[8] = {fa.x, fa.y, fa.z, fa.w, fb4.x, fb4.y, fb4.z, fb4.w};
        float qv[8] = {qa.x, qa.y, qa.z, qa.w, qd.x, qd.y, qd.z, qd.w};
        float S2 = S2g;
#pragma unroll
        for (int s = 0; s < 8; ++s) {
            float qb = ks * fpow(S2 * invS2, nn);
            rr[s * ROWS + (lane - (WIN_FC - 8))] = fxv[s] + qb;
            S2 = fminf(fmaxf(S2 + qv[s] - qb, 0.0f), S2max);
        }
    }
    // routing weights -> LDS (read back as wave-uniform broadcast in the conv)
    {
        float delay = physp(raw, 21, 0.01f, 5.0f);  // mu_t
        float theta = fmaxf(delay, 1e-3f) * (1.0f / 2.5f);
        float tt = (float)lane + 0.5f;
        float logk = 1.5f * LOG2F(tt) * 0.6931471805599453f - tt / theta;  // ln(t)=log2(t)*ln2
        float m = logk;
#pragma unroll
        for (int o = 32; o >= 1; o >>= 1) m = fmaxf(m, __shfl_xor(m, o, 64));
        float e = __expf(logk - m);
        float su = e;
#pragma unroll
        for (int o = 32; o >= 1; o >>= 1) su += __shfl_xor(su, o, 64);
        kerL[lane] = e / su;
    }
    __syncthreads();

    // ---- 64-tap conv, register sliding window: lane computes its own chunk's 8 outputs ----
    // y[s] = sum_k ker[k] * x[8*lane+s-k]; jj-loop (k=63-jj) slides window up by 1/iter.
    // Negligible-tap skip: gamma tail weights < 1e-12 contribute < 3e-9 total; the
    // wave-uniform branch skips their 8 FMAs (window slide still runs).
    {
        float y[8];
#pragma unroll
        for (int s = 0; s < 8; ++s) y[s] = 0.0f;
        float wdw[8];
        // initial window: x[8*lane-63 .. 8*lane-56]  (m = 8*lane+1+e)
#pragma unroll
        for (int e = 0; e < 8; ++e) {
            int m = 8 * lane + 1 + e;
            wdw[e] = rr[(m & 7) * ROWS + (m >> 3)];
        }
#pragma unroll
        for (int jj = 0; jj < 64; ++jj) {
            float kk = kerL[63 - jj];  // uniform address -> LDS broadcast
            if (kk > 1e-12f) {
#pragma unroll
                for (int s = 0; s < 8; ++s) y[s] += kk * wdw[(jj + s) & 7];
            }
            if (jj < 63) {
                int m = 8 * lane + 9 + jj;  // new element x[8*lane-55+jj]
                wdw[jj & 7] = rr[(m & 7) * ROWS + (m >> 3)];
            }
        }
        int tb = w * WSTEP + 8 * lane;
        if (tb + 8 <= T) {
            float4* op = (float4*)(out + tb);
            op[0] = make_float4(y[0], y[1], y[2], y[3]);
            op[1] = make_float4(y[4], y[5], y[6], y[7]);
        } else {
            for (int s = 0; s < 8; ++s)
                if (tb + s < T) out[tb + s] = y[s];
        }
    }
}

extern "C" void kernel_launch(void* const* d_in, const int* in_sizes, int n_in,
                              void* d_out, int out_size, void* d_ws, size_t ws_size,
                              hipStream_t stream) {
    const float* forcing = (const float*)d_in[0];  // [T,3]
    const float* raw = (const float*)d_in[1];      // [29]
    float* out = (float*)d_out;
    float* ws = (float*)d_ws;

    int T = in_sizes[0] / 3;
    int nfine = (T + FCH - 1) / FCH;              // 16384 for T=131072
    int NW = (nfine + WIN_FC - 1) / WIN_FC;       // 256
    int P = ((nfine + 15) / 16) * 16;
    int PW = ((NW + 15) / 16) * 16;
    int Tp = P * FCH;

    float* q12f = ws;            // [P]   per-chunk q12 sum
    float* Qw = q12f + P;        // [PW]  per-window inflow
    float* fxg = Qw + PW;        // [Tp]  per-step qsx+qif
    float* q12g = fxg + Tp;      // [Tp]  per-step q12

    k_a<<<NW, 64, 0, stream>>>(forcing, raw, q12f, Qw, fxg, q12g, T, nfine);
    k_b<<<NW, 64, 0, stream>>>(raw, q12f, Qw, fxg, q12g, out, T, nfine, NW);
}